// Round 7
// baseline (155.752 us; speedup 1.0000x reference)
//
#include <hip/hip_runtime.h>

// GNNComm: out[i,:] = mean_{j!=i} relu(concat(m_i,m_j)@W1^T + b1) @ W2^T + b2
// N=2048, D=8, H=64.
//
// relu(z) = (z+|z|)/2 =>
//   S[i,h] = 0.5*(N*a_ih + SX_h + C_ih), C_ih = sum_j |a_ih + x_jh|
//   a = X1[i]+b1, x = X2[j], SX = sum_j x_jh
// out[i,d] = 0.5*sum_h (C_ih + SX_h + N*a_ih - 2*relu(a_ih+x_ih)) W2[d,h]
//            / (N-1) + b2[d]
//
// R6 post-mortem: atomic-free pair (good) but the extra reduce dispatch +
// gap (~4us) ate the savings; 2-dispatch R3 still held the record because
// dispatch overhead ~ atomic drain. This version: 2 dispatches AND no
// atomic drain. Pair blocks plain-store partials P[jc][i][d], release-fence
// (__threadfence -> buffer_wbl2, cross-XCD visible), bump a per-i-tile
// counter; the 32nd block acquire-fences and reduces P -> out (+b2, scale).
// Only 1024 counter atomics total; out needs no pre-zeroing.

#define NN 2048
#define HH 64
#define DD 8

#define ITILES 32          // 32 i-tiles x 64 i
#define JCHUNKS 32         // 32 j-chunks x 64 j
#define JCHUNK (NN / JCHUNKS)
#define INV_SCALE (0.5f / (float)(NN - 1))

// --- K1: A[i,h] = X1[i,h]+b1[h]; X2[i,h]; zero tile counters ---
__global__ void prep_kernel(const float* __restrict__ msg,
                            const float* __restrict__ W1,
                            const float* __restrict__ b1,
                            float* __restrict__ A,
                            float* __restrict__ X2,
                            int* __restrict__ cnt) {
    int idx = blockIdx.x * blockDim.x + threadIdx.x;  // 0 .. N*H-1
    if (idx < ITILES) cnt[idx] = 0;
    int i = idx >> 6;
    int h = idx & 63;
    const float4* m4 = (const float4*)(msg + i * DD);
    const float4* w4 = (const float4*)(W1 + h * (2 * DD));
    float4 m0 = m4[0], m1 = m4[1];
    float4 w0 = w4[0], w1 = w4[1], w2 = w4[2], w3 = w4[3];
    float x1 = m0.x * w0.x + m0.y * w0.y + m0.z * w0.z + m0.w * w0.w
             + m1.x * w1.x + m1.y * w1.y + m1.z * w1.z + m1.w * w1.w;
    float x2 = m0.x * w2.x + m0.y * w2.y + m0.z * w2.z + m0.w * w2.w
             + m1.x * w3.x + m1.y * w3.y + m1.z * w3.z + m1.w * w3.w;
    A[idx]  = x1 + b1[h];
    X2[idx] = x2;
}

// --- K2: pairwise |a+x|, register W2-projection, P stores, last-block reduce ---
// Block (it,jc): 64 i x 64 h x 64 j. Thread: hq=tid&15 (4 h's), il=tid>>4 (4 i's).
__global__ void __launch_bounds__(256, 4)
pair_kernel(const float* __restrict__ A,
            const float* __restrict__ X2,
            const float* __restrict__ W2,
            const float* __restrict__ b2,
            float* __restrict__ P,
            int* __restrict__ cnt,
            float* __restrict__ out) {
    __shared__ float sX2f[JCHUNK * HH];   // 16 KB: [64 j][64 h]
    __shared__ float sSX[HH];             // chunk column sums
    __shared__ int sIsLast;

    int it = blockIdx.x & (ITILES - 1);
    int jc = blockIdx.x >> 5;             // 0..31
    int hq = threadIdx.x & 15;
    int il = threadIdx.x >> 4;
    int h0 = hq * 4;
    int i0 = it * 64 + il * 4;
    bool des = (jc == it);                // diagonal block owns per-i terms

    // stage X2 chunk: 1024 float4, 4 per thread (coalesced)
    {
        const float4* src = (const float4*)(X2 + jc * JCHUNK * HH);
        float4* dst = (float4*)sX2f;
#pragma unroll
        for (int r = 0; r < 4; ++r)
            dst[threadIdx.x + r * 256] = src[threadIdx.x + r * 256];
    }

    float a[4][4];
#pragma unroll
    for (int k = 0; k < 4; ++k) {
        float4 av = *(const float4*)&A[(i0 + k) * HH + h0];
        a[k][0] = av.x; a[k][1] = av.y; a[k][2] = av.z; a[k][3] = av.w;
    }
    float acc[4][4];
#pragma unroll
    for (int k = 0; k < 4; ++k)
#pragma unroll
        for (int hh = 0; hh < 4; ++hh)
            acc[k][hh] = 0.f;

    __syncthreads();

    // ---- hot loop: 2 VALU/elem (add + add-with-|.|-modifier) ----
    const float4* sX2v = (const float4*)sX2f;
#pragma unroll 4
    for (int j = 0; j < JCHUNK; ++j) {
        float4 x = sX2v[j * 16 + hq];
#pragma unroll
        for (int k = 0; k < 4; ++k) {
            acc[k][0] += __builtin_fabsf(a[k][0] + x.x);
            acc[k][1] += __builtin_fabsf(a[k][1] + x.y);
            acc[k][2] += __builtin_fabsf(a[k][2] + x.z);
            acc[k][3] += __builtin_fabsf(a[k][3] + x.w);
        }
    }

    // chunk column-sums (wave 0 only; hidden by other waves)
    if (threadIdx.x < 64) {
        float s0 = 0.f, s1 = 0.f, s2 = 0.f, s3 = 0.f;
#pragma unroll 4
        for (int j = 0; j < JCHUNK; j += 4) {
            s0 += sX2f[(j + 0) * HH + threadIdx.x];
            s1 += sX2f[(j + 1) * HH + threadIdx.x];
            s2 += sX2f[(j + 2) * HH + threadIdx.x];
            s3 += sX2f[(j + 3) * HH + threadIdx.x];
        }
        sSX[threadIdx.x] = (s0 + s1) + (s2 + s3);
    }
    __syncthreads();

    // diagonal fold: local j == local i on the jc==it block
    if (des) {
        int jlb = il * 4;
#pragma unroll
        for (int k = 0; k < 4; ++k) {
            float4 xd = *(const float4*)&sX2f[(jlb + k) * HH + h0];
            float z0 = a[k][0] + xd.x, z1 = a[k][1] + xd.y;
            float z2 = a[k][2] + xd.z, z3 = a[k][3] + xd.w;
            acc[k][0] += (float)NN * a[k][0] - 2.f * (z0 > 0.f ? z0 : 0.f);
            acc[k][1] += (float)NN * a[k][1] - 2.f * (z1 > 0.f ? z1 : 0.f);
            acc[k][2] += (float)NN * a[k][2] - 2.f * (z2 > 0.f ? z2 : 0.f);
            acc[k][3] += (float)NN * a[k][3] - 2.f * (z3 > 0.f ? z3 : 0.f);
        }
    }

    // fold chunk-SX into acc (its W2-projection comes along for free)
    {
        float4 sx = *(const float4*)&sSX[h0];
#pragma unroll
        for (int k = 0; k < 4; ++k) {
            acc[k][0] += sx.x; acc[k][1] += sx.y;
            acc[k][2] += sx.z; acc[k][3] += sx.w;
        }
    }

    // W2 fragment: this lane's 4 h-columns for all 8 d (L1/L2-hot)
    float4 w[8];
    {
        const float4* w2v = (const float4*)W2;  // [8][16]
#pragma unroll
        for (int d = 0; d < 8; ++d)
            w[d] = w2v[d * 16 + hq];
    }

    // per i-row: project onto W2, shfl-reduce over hq lanes, plain store to P
#pragma unroll
    for (int k = 0; k < 4; ++k) {
        float p[8];
#pragma unroll
        for (int d = 0; d < 8; ++d)
            p[d] = acc[k][0] * w[d].x + acc[k][1] * w[d].y
                 + acc[k][2] * w[d].z + acc[k][3] * w[d].w;
#pragma unroll
        for (int m = 1; m < 16; m <<= 1)
#pragma unroll
            for (int d = 0; d < 8; ++d)
                p[d] += __shfl_xor(p[d], m);
        if (hq < 8) {
            float pv = p[0];
            pv = (hq == 1) ? p[1] : pv;
            pv = (hq == 2) ? p[2] : pv;
            pv = (hq == 3) ? p[3] : pv;
            pv = (hq == 4) ? p[4] : pv;
            pv = (hq == 5) ? p[5] : pv;
            pv = (hq == 6) ? p[6] : pv;
            pv = (hq == 7) ? p[7] : pv;
            P[(jc * NN + i0 + k) * DD + hq] = pv;
        }
    }

    // ---- last-block-per-i-tile reduction: P[0..31][it-tile] -> out ----
    __threadfence();  // release: make our P stores device-visible (wbl2)
    if (threadIdx.x == 0)
        sIsLast = (atomicAdd(&cnt[it], 1) == JCHUNKS - 1);
    __syncthreads();
    if (sIsLast) {
        __threadfence();  // acquire: invalidate stale cached P lines
        // 512 (i,d) slots for this tile; thread t handles slots t, t+256
#pragma unroll
        for (int r = 0; r < 2; ++r) {
            int s = threadIdx.x + r * 256;       // 0..511
            int base = it * 512 + s;             // flat (i*DD+d) offset
            float sum = 0.f;
#pragma unroll 8
            for (int j = 0; j < JCHUNKS; ++j)
                sum += P[j * (NN * DD) + base];  // coalesced per j-plane
            out[base] = sum * INV_SCALE + b2[s & 7];
        }
    }
}

extern "C" void kernel_launch(void* const* d_in, const int* in_sizes, int n_in,
                              void* d_out, int out_size, void* d_ws, size_t ws_size,
                              hipStream_t stream) {
    const float* msg = (const float*)d_in[0];  // [N, 8]
    const float* W1  = (const float*)d_in[1];  // [64, 16]
    const float* b1  = (const float*)d_in[2];  // [64]
    const float* W2  = (const float*)d_in[3];  // [8, 64]
    const float* b2  = (const float*)d_in[4];  // [8]
    float* out = (float*)d_out;                // [N, 8]

    float* ws = (float*)d_ws;
    float* A  = ws;                   // N*H floats
    float* X2 = ws + NN * HH;         // N*H floats
    float* P  = ws + 2 * NN * HH;     // JCHUNKS*N*D floats (2 MB)
    int*   cnt = (int*)(P + JCHUNKS * NN * DD);  // 32 ints

    prep_kernel<<<(NN * HH) / 256, 256, 0, stream>>>(msg, W1, b1, A, X2, cnt);
    pair_kernel<<<ITILES * JCHUNKS, 256, 0, stream>>>(A, X2, W2, b2, P, cnt, out);
}

// Round 8
// 103.802 us; speedup vs baseline: 1.5005x; 1.5005x over previous
//
#include <hip/hip_runtime.h>

// GNNComm: out[i,:] = mean_{j!=i} relu(concat(m_i,m_j)@W1^T + b1) @ W2^T + b2
// N=2048, D=8, H=64.
//
// relu(z) = (z+|z|)/2 =>
//   S[i,h] = 0.5*(N*a_ih + SX_h + C_ih), C_ih = sum_j |a_ih + x_jh|
//   a = X1[i]+b1, x = X2[j], SX = sum_j x_jh
// out[i,d] = 0.5*sum_h (C_ih + SX_h + N*a_ih - 2*relu(a_ih+x_ih)) W2[d,h]
//            / (N-1) + b2[d]
//
// R7 post-mortem: last-block reduction needs a device-scope release fence
// in EVERY block; on gfx950 that's buffer_wbl2 (per-XCD L2 writeback) x1024
// -> 99us. Lesson: cross-XCD visibility machinery is O(1)-per-launch only.
// This version removes cross-block coupling entirely: each block owns 4 i
// rows COMPLETELY (all 2048 j), merges its 16 per-thread j-slices in LDS,
// projects onto W2, and plain-stores its 4x8 out rows. Zero atomics, zero
// fences, no P, no zeroing. Grid 512 = exactly 2 blocks/CU. X2 read
// directly from global (512KB, L2-resident).

#define NN 2048
#define HH 64
#define DD 8

#define IB 4               // i rows per block
#define JS 16              // j-slices per block (one per il group)
#define JSL (NN / JS)      // 128 j per slice
#define INV_SCALE (0.5f / (float)(NN - 1))

// --- K1: A[i,h] = X1[i,h]+b1[h]; X2[i,h] ---
__global__ void prep_kernel(const float* __restrict__ msg,
                            const float* __restrict__ W1,
                            const float* __restrict__ b1,
                            float* __restrict__ A,
                            float* __restrict__ X2) {
    int idx = blockIdx.x * blockDim.x + threadIdx.x;  // 0 .. N*H-1
    int i = idx >> 6;
    int h = idx & 63;
    const float4* m4 = (const float4*)(msg + i * DD);
    const float4* w4 = (const float4*)(W1 + h * (2 * DD));
    float4 m0 = m4[0], m1 = m4[1];
    float4 w0 = w4[0], w1 = w4[1], w2 = w4[2], w3 = w4[3];
    float x1 = m0.x * w0.x + m0.y * w0.y + m0.z * w0.z + m0.w * w0.w
             + m1.x * w1.x + m1.y * w1.y + m1.z * w1.z + m1.w * w1.w;
    float x2 = m0.x * w2.x + m0.y * w2.y + m0.z * w2.z + m0.w * w2.w
             + m1.x * w3.x + m1.y * w3.y + m1.z * w3.z + m1.w * w3.w;
    A[idx]  = x1 + b1[h];
    X2[idx] = x2;
}

// --- K2: block owns i0..i0+3 fully; thread = 4i x 4h x 128j slice ---
__global__ void __launch_bounds__(256, 2)
pair_kernel(const float* __restrict__ A,
            const float* __restrict__ X2,
            const float* __restrict__ W2,
            const float* __restrict__ b2,
            float* __restrict__ out) {
    __shared__ float sT[JS][IB][HH];   // per-slice |.|-partials, 16 KB
    __shared__ float sS[JS][HH];       // per-slice x column-sums, 4 KB

    int it = blockIdx.x;               // 0..511: i-tile
    int hq = threadIdx.x & 15;         // 4 h's
    int js = threadIdx.x >> 4;         // j-slice 0..15
    int h0 = hq * 4;
    int i0 = it * IB;

    // a-frags for the block's 4 i rows (same for every thread)
    float a[IB][4];
#pragma unroll
    for (int k = 0; k < IB; ++k) {
        float4 av = *(const float4*)&A[(i0 + k) * HH + h0];
        a[k][0] = av.x; a[k][1] = av.y; a[k][2] = av.z; a[k][3] = av.w;
    }
    float acc[IB][4];
#pragma unroll
    for (int k = 0; k < IB; ++k)
#pragma unroll
        for (int hh = 0; hh < 4; ++hh)
            acc[k][hh] = 0.f;
    float accS[4] = {0.f, 0.f, 0.f, 0.f};

    // ---- hot loop over this thread's 128-j slice (global reads, L2-hot) ----
    const float4* X2v = (const float4*)X2;  // row j = 16 float4
    int jbase = js * JSL;
#pragma unroll 8
    for (int j = jbase; j < jbase + JSL; ++j) {
        float4 x = X2v[j * 16 + hq];
        accS[0] += x.x; accS[1] += x.y; accS[2] += x.z; accS[3] += x.w;
#pragma unroll
        for (int k = 0; k < IB; ++k) {
            acc[k][0] += __builtin_fabsf(a[k][0] + x.x);
            acc[k][1] += __builtin_fabsf(a[k][1] + x.y);
            acc[k][2] += __builtin_fabsf(a[k][2] + x.z);
            acc[k][3] += __builtin_fabsf(a[k][3] + x.w);
        }
    }

    // write per-slice partials to LDS
#pragma unroll
    for (int k = 0; k < IB; ++k)
        *(float4*)&sT[js][k][h0] =
            make_float4(acc[k][0], acc[k][1], acc[k][2], acc[k][3]);
    *(float4*)&sS[js][h0] = make_float4(accS[0], accS[1], accS[2], accS[3]);
    __syncthreads();

    // ---- merge + epilogue: 64 threads, one per (i, hq) ----
    if (threadIdx.x < 64) {
        int i = threadIdx.x >> 4;      // 0..3
        int q = threadIdx.x & 15;      // 0..15
        int qh = q * 4;

        float4 C = make_float4(0.f, 0.f, 0.f, 0.f);
        float4 S = make_float4(0.f, 0.f, 0.f, 0.f);
#pragma unroll
        for (int s = 0; s < JS; ++s) {
            float4 t = *(const float4*)&sT[s][i][qh];
            float4 u = *(const float4*)&sS[s][qh];
            C.x += t.x; C.y += t.y; C.z += t.z; C.w += t.w;
            S.x += u.x; S.y += u.y; S.z += u.z; S.w += u.w;
        }
        float4 av = *(const float4*)&A[(i0 + i) * HH + qh];
        float4 xi = *(const float4*)&X2[(i0 + i) * HH + qh];
        float z0 = av.x + xi.x, z1 = av.y + xi.y;
        float z2 = av.z + xi.z, z3 = av.w + xi.w;
        float v0 = C.x + S.x + (float)NN * av.x - 2.f * (z0 > 0.f ? z0 : 0.f);
        float v1 = C.y + S.y + (float)NN * av.y - 2.f * (z1 > 0.f ? z1 : 0.f);
        float v2 = C.z + S.z + (float)NN * av.z - 2.f * (z2 > 0.f ? z2 : 0.f);
        float v3 = C.w + S.w + (float)NN * av.w - 2.f * (z3 > 0.f ? z3 : 0.f);

        // project onto W2 (this lane's 4 h-columns), reduce over the 16 q lanes
        const float4* w2v = (const float4*)W2;  // [8][16]
        float p[8];
#pragma unroll
        for (int d = 0; d < 8; ++d) {
            float4 w = w2v[d * 16 + q];
            p[d] = v0 * w.x + v1 * w.y + v2 * w.z + v3 * w.w;
        }
#pragma unroll
        for (int m = 1; m < 16; m <<= 1)
#pragma unroll
            for (int d = 0; d < 8; ++d)
                p[d] += __shfl_xor(p[d], m);

        if (q < 8) {
            float pv = p[0];
            pv = (q == 1) ? p[1] : pv;
            pv = (q == 2) ? p[2] : pv;
            pv = (q == 3) ? p[3] : pv;
            pv = (q == 4) ? p[4] : pv;
            pv = (q == 5) ? p[5] : pv;
            pv = (q == 6) ? p[6] : pv;
            pv = (q == 7) ? p[7] : pv;
            out[(i0 + i) * DD + q] = pv * INV_SCALE + b2[q];
        }
    }
}

extern "C" void kernel_launch(void* const* d_in, const int* in_sizes, int n_in,
                              void* d_out, int out_size, void* d_ws, size_t ws_size,
                              hipStream_t stream) {
    const float* msg = (const float*)d_in[0];  // [N, 8]
    const float* W1  = (const float*)d_in[1];  // [64, 16]
    const float* b1  = (const float*)d_in[2];  // [64]
    const float* W2  = (const float*)d_in[3];  // [8, 64]
    const float* b2  = (const float*)d_in[4];  // [8]
    float* out = (float*)d_out;                // [N, 8]

    float* ws = (float*)d_ws;
    float* A  = ws;            // N*H floats
    float* X2 = ws + NN * HH;  // N*H floats

    prep_kernel<<<(NN * HH) / 256, 256, 0, stream>>>(msg, W1, b1, A, X2);
    pair_kernel<<<NN / IB, 256, 0, stream>>>(A, X2, W2, b2, out);
}